// Round 7
// baseline (1318.618 us; speedup 1.0000x reference)
//
#include <hip/hip_runtime.h>
#include <stdint.h>

// B=2, SQ=SK=2048, HIDDEN=2048, HEADS=16, HEAD_DIM=128.
// DTYPE MODEL (verified): inputs fp32, mask int32, OUTPUT fp32. Internal bf16 MFMA.
// Round 15: attn v6 + proj unchanged (both verified). QKV gemm256 v2: BK=32
// double-buffer, LDS 64 KiB -> 2 blocks/CU (384 blocks ALL co-resident, no
// second dispatch round), one __syncthreads per 32-K chunk with cross-barrier
// glds prefetch (m97 pattern scaled to 32 MFMA + 12 ds_read per barrier).
// Rationale: at 1 block/CU (128 KiB) neither counted-vmcnt nor extra phases
// can hide sync stalls (r11 neutral); TLP from a co-resident block can (m114).

#define LOG2E 1.44269504088896340736f
#define INV2PI 0.15915494309189535f

typedef __attribute__((ext_vector_type(8))) short bf16x8;
typedef __attribute__((ext_vector_type(8))) uint16_t u16x8;
typedef __attribute__((ext_vector_type(4))) uint16_t u16x4;
typedef __attribute__((ext_vector_type(4))) float f32x4;

__device__ __forceinline__ uint16_t f2bf(float f) {
  union { float f; uint32_t i; } v; v.f = f;
  uint32_t x = v.i;
  return (uint16_t)((x + 0x7fffu + ((x >> 16) & 1u)) >> 16);  // RTN-even
}
__device__ __forceinline__ uint32_t f_as_u(float f) { union { float f; uint32_t u; } v; v.f = f; return v.u; }
__device__ __forceinline__ float u_as_f(uint32_t u) { union { uint32_t u; float f; } v; v.u = u; return v.f; }
__device__ __forceinline__ void glds16(const void* g, void* l) {
  __builtin_amdgcn_global_load_lds((const __attribute__((address_space(1))) void*)g,
                                   (__attribute__((address_space(3))) void*)l, 16, 0, 0);
}

// fp32 -> bf16, 8 elems/thread, exact grid (n % 2048 == 0).
__global__ __launch_bounds__(256) void convert_f32_bf16(const float* __restrict__ in,
                                                        uint16_t* __restrict__ out) {
  const long i = ((long)blockIdx.x * 256 + threadIdx.x) * 8;
  const f32x4 a = *(const f32x4*)(in + i);
  const f32x4 b = *(const f32x4*)(in + i + 4);
  u16x8 o;
#pragma unroll
  for (int j = 0; j < 4; ++j) { o[j] = f2bf(a[j]); o[4 + j] = f2bf(b[j]); }
  *(u16x8*)(out + i) = o;
}

// All four weights -> one contiguous bf16 buffer W4 = [Wq|Wk|Wv|Wo], 4M elems each.
__global__ __launch_bounds__(256) void convert_w4(const float* __restrict__ Wq,
                                                  const float* __restrict__ Wk,
                                                  const float* __restrict__ Wv,
                                                  const float* __restrict__ Wo,
                                                  uint16_t* __restrict__ W4) {
  const int blk = blockIdx.x;        // 8192 blocks, 2048 per section
  const int sec = blk >> 11;
  const long off = ((long)(blk & 2047) * 256 + threadIdx.x) * 8;
  const float* src = (sec == 0) ? Wq : (sec == 1) ? Wk : (sec == 2) ? Wv : Wo;
  const f32x4 a = *(const f32x4*)(src + off);
  const f32x4 b = *(const f32x4*)(src + off + 4);
  u16x8 o;
#pragma unroll
  for (int j = 0; j < 4; ++j) { o[j] = f2bf(a[j]); o[4 + j] = f2bf(b[j]); }
  *(u16x8*)(W4 + (long)sec * 4194304 + off) = o;
}

// mask int -> additive softmax bias float (0 or -inf). 4096 elems.
__global__ __launch_bounds__(256) void mask_bias(const int* __restrict__ m,
                                                 float* __restrict__ bias) {
  const int i = blockIdx.x * 256 + threadIdx.x;
  bias[i] = m[i] ? 0.0f : -__builtin_inff();
}

// c is the section-local column; C has row stride 2048.
__device__ __forceinline__ void epi_rope_store(uint16_t* C, const f32x4& a, int rowbase,
                                               int c, float oscale) {
  const int f = (c >> 1) & 63;
  const float inv = __builtin_amdgcn_exp2f((float)f * (-13.287712379549449f / 64.0f));
  const float sgn = (c & 1) ? 1.0f : -1.0f;
#pragma unroll
  for (int r = 0; r < 4; ++r) {
    const float val = a[r];
    const float partner = __shfl_xor(val, 1);
    const int s = (rowbase + r) & 2047;
    const float rev = __builtin_amdgcn_fractf((float)s * inv * INV2PI);
    const float sn = __builtin_amdgcn_sinf(rev);
    const float cs = __builtin_amdgcn_cosf(rev);
    C[(long)(rowbase + r) * 2048 + c] = f2bf((val * cs + sgn * partner * sn) * oscale);
  }
}

// ---------------------------------------------------------------------------
// QKV mega-GEMM v2: 256x256 tile, BK=32, 512 threads = 8 waves (2M x 4N),
// wave tile 128x64.  LDS 64 KiB (2 blocks/CU): As/Bs = [2][256*32].
// One __syncthreads per chunk; chunk c+1 staged cross-barrier during c.
// LDS plane map: [256 rows][4 slots of 8]; phys slot p at row r holds logical
// k-slot p ^ ((r>>1)&3); staged via pre-swizzled global source (rule 21).
// ---------------------------------------------------------------------------
__global__ __launch_bounds__(512, 4) void gemm256(const uint16_t* __restrict__ A0,
                                                  const uint16_t* __restrict__ A1,
                                                  const uint16_t* __restrict__ W,
                                                  uint16_t* __restrict__ Qb,
                                                  uint16_t* __restrict__ Kb,
                                                  uint16_t* __restrict__ Vtb,
                                                  int M, int N, int K, float oscale) {
  __shared__ __align__(16) uint16_t As[2][8192];  // [buf][256*32] = 32 KiB
  __shared__ __align__(16) uint16_t Bs[2][8192];  // 32 KiB
  const int tid = threadIdx.x;
  const int lane = tid & 63;
  const int w = tid >> 6;
  const int r16 = lane & 15, quad = lane >> 4;
  const int wm = w >> 2, wn = w & 3;

  // bijective XCD swizzle (nwg % 8 == 0), column-chunked.
  const int nby = M >> 8;
  const int nwg = gridDim.x;
  const int wg = ((int)blockIdx.x & 7) * (nwg >> 3) + ((int)blockIdx.x >> 3);
  const int by = wg % nby, bx = wg / nby;
  const int m0 = by << 8, n0 = bx << 8;

  const uint16_t* A = (n0 >= 2048) ? A1 : A0;

  // staging: wave w owns rows 32w..32w+31 (two 16-row chunks) of each plane
  const int srow = 2 * w * 16 + (lane >> 2);           // rows srow, srow+16
  const int ssl = (lane & 3) ^ ((srow >> 1) & 3);      // same for srow+16
  const uint16_t* Ag0 = A + (long)(m0 + srow) * K + ssl * 8;
  const uint16_t* Ag1 = Ag0 + (long)16 * K;
  const uint16_t* Bg0 = W + (long)(n0 + srow) * K + ssl * 8;
  const uint16_t* Bg1 = Bg0 + (long)16 * K;
  const int ldso = w << 10;  // element offset of this wave's first 1 KiB chunk

  // fragment read offsets (elements within one plane)
  const int sw = (r16 >> 1) & 3;
  const int aoff = (wm * 128 + r16) * 32 + ((quad ^ sw) << 3);
  const int boff = (wn * 64 + r16) * 32 + ((quad ^ sw) << 3);

  f32x4 acc[8][4] = {};
  bf16x8 af[4], bfr[4];

#define G_STAGE(BUF, C) do { \
    glds16(Ag0 + (long)(C) * 32, &As[BUF][ldso]); \
    glds16(Ag1 + (long)(C) * 32, &As[BUF][ldso + 512]); \
    glds16(Bg0 + (long)(C) * 32, &Bs[BUF][ldso]); \
    glds16(Bg1 + (long)(C) * 32, &Bs[BUF][ldso + 512]); } while (0)
#define LDS_B(BUF) do { _Pragma("unroll") \
    for (int i = 0; i < 4; ++i) bfr[i] = *(const bf16x8*)&Bs[BUF][boff + i * 512]; } while (0)
#define LDS_A(BUF, MH) do { _Pragma("unroll") \
    for (int i = 0; i < 4; ++i) af[i] = *(const bf16x8*)&As[BUF][aoff + ((MH) * 4 + i) * 512]; } while (0)
#define MFMA16(MH) do { __builtin_amdgcn_s_setprio(1); _Pragma("unroll") \
    for (int mi = 0; mi < 4; ++mi) { _Pragma("unroll") \
      for (int nt = 0; nt < 4; ++nt) \
        acc[(MH) * 4 + mi][nt] = __builtin_amdgcn_mfma_f32_16x16x32_bf16(af[mi], bfr[nt], acc[(MH) * 4 + mi][nt], 0, 0, 0); } \
    __builtin_amdgcn_s_setprio(0); } while (0)

  // prologue: stage chunk 0 into buf 0, drain
  G_STAGE(0, 0);
  __syncthreads();

  const int NC = K >> 5;  // 64 chunks of 32
  for (int c = 0; c < NC; ++c) {
    const int cur = c & 1;
    if (c + 1 < NC) G_STAGE(cur ^ 1, c + 1);   // cross-barrier prefetch
    LDS_B(cur);
    LDS_A(cur, 0); MFMA16(0);
    LDS_A(cur, 1); MFMA16(1);
    __syncthreads();  // drains chunk c+1 loads; frees buf cur for c+2
  }

#undef G_STAGE
#undef LDS_A
#undef LDS_B
#undef MFMA16

#pragma unroll
  for (int mt = 0; mt < 8; ++mt)
#pragma unroll
    for (int nt = 0; nt < 4; ++nt) {
      const int col = n0 + wn * 64 + nt * 16 + r16;
      const int rowbase = m0 + wm * 128 + mt * 16 + quad * 4;
      if (n0 < 2048) {
        epi_rope_store(Qb, acc[mt][nt], rowbase, col, oscale);       // Q
      } else if (n0 < 4096) {
        epi_rope_store(Kb, acc[mt][nt], rowbase, col - 2048, 1.0f);  // K
      } else {
        const int c = col - 4096;
        const int h = c >> 7, d = c & 127;
        const int b = rowbase >> 11, s = rowbase & 2047;
        u16x4 pk;
#pragma unroll
        for (int r = 0; r < 4; ++r) pk[r] = f2bf(acc[mt][nt][r]);
        *(u16x4*)(Vtb + (long)((b * 16 + h) * 128 + d) * 2048 + s) = pk;
      }
    }
}

// ---------------------------------------------------------------------------
// Final projection: BM=128, BN=256, BK=64, 8 waves (2M x 4N) -> wave 64x64.
// Grid 32x8 = 256 blocks = one full round on 256 CUs.  vmcnt(3) ledger.
// LDS: As 2x2x[128x32]=32K + Bs 2x2x[256x32]=64K = 96 KiB.
// ---------------------------------------------------------------------------
__global__ __launch_bounds__(512, 2) void gemm_proj(const uint16_t* __restrict__ A0,
                                                    const uint16_t* __restrict__ W,
                                                    float* __restrict__ C,
                                                    int M, int N, int K) {
  __shared__ __align__(16) uint16_t As[2][2][4096];  // [buf][kk][128*32] = 32 KiB
  __shared__ __align__(16) uint16_t Bs[2][2][8192];  // [buf][kk][256*32] = 64 KiB
  const int tid = threadIdx.x;
  const int lane = tid & 63;
  const int w = tid >> 6;
  const int r16 = lane & 15, quad = lane >> 4;
  const int wm = w >> 2, wn = w & 3;

  const int nby = M >> 7;  // BM=128
  const int nwg = gridDim.x;
  const int wg = ((int)blockIdx.x & 7) * (nwg >> 3) + ((int)blockIdx.x >> 3);
  const int by = wg % nby, bx = wg / nby;
  const int m0 = by << 7, n0 = bx << 8;

  // staging: wave w owns A chunk w (16 rows) and B chunks 2w, 2w+1
  const int sa_row = 16 * w + (lane >> 2);
  const int sb_row = 32 * w + (lane >> 2);
  const int ssl = (lane & 3) ^ (((lane >> 2) >> 1) & 3);
  const uint16_t* Ag = A0 + (long)(m0 + sa_row) * K + ssl * 8;
  const uint16_t* Bg0 = W + (long)(n0 + sb_row) * K + ssl * 8;
  const uint16_t* Bg1 = Bg0 + (long)16 * K;

  const int sw = (r16 >> 1) & 3;
  const int aoff = (wm * 64 + r16) * 32 + ((quad ^ sw) << 3);
  const int boff = (wn * 64 + r16) * 32 + ((quad ^ sw) << 3);

  f32x4 acc[4][4] = {};
  bf16x8 af[4], bfr[4];

#define SCHED0() __builtin_amdgcn_sched_barrier(0)
#define VMBAR(NN) do { SCHED0(); \
    asm volatile("s_waitcnt vmcnt(" #NN ")" ::: "memory"); \
    __builtin_amdgcn_s_barrier(); \
    SCHED0(); } while (0)
#define PG_STAGE_A(BUF, KK, T) \
    glds16(Ag + (long)(T) * 64 + (KK) * 32, &As[BUF][KK][w * 512])
#define PG_STAGE_B(BUF, KK, T) do { \
    glds16(Bg0 + (long)(T) * 64 + (KK) * 32, &Bs[BUF][KK][2 * w * 512]); \
    glds16(Bg1 + (long)(T) * 64 + (KK) * 32, &Bs[BUF][KK][2 * w * 512 + 512]); } while (0)
#define PLDS_B(BUF, KK) do { _Pragma("unroll") \
    for (int i = 0; i < 4; ++i) bfr[i] = *(const bf16x8*)&Bs[BUF][KK][boff + i * 512]; } while (0)
#define PLDS_A(BUF, KK) do { _Pragma("unroll") \
    for (int i = 0; i < 4; ++i) af[i] = *(const bf16x8*)&As[BUF][KK][aoff + i * 512]; } while (0)
#define PMFMA(MT0, MT1) do { __builtin_amdgcn_s_setprio(1); _Pragma("unroll") \
    for (int mi = (MT0); mi < (MT1); ++mi) { _Pragma("unroll") \
      for (int nt = 0; nt < 4; ++nt) \
        acc[mi][nt] = __builtin_amdgcn_mfma_f32_16x16x32_bf16(af[mi], bfr[nt], acc[mi][nt], 0, 0, 0); } \
    __builtin_amdgcn_s_setprio(0); } while (0)
#define PTILE(T, BC, BN) do { \
    PG_STAGE_A(BN, 0, (T) + 1); PLDS_B(BC, 0); PLDS_A(BC, 0); PMFMA(0, 2); \
    PG_STAGE_B(BN, 0, (T) + 1); PMFMA(2, 4); \
    VMBAR(3); \
    PG_STAGE_A(BN, 1, (T) + 1); PLDS_B(BC, 1); PLDS_A(BC, 1); PMFMA(0, 2); \
    PG_STAGE_B(BN, 1, (T) + 1); PMFMA(2, 4); \
    VMBAR(3); } while (0)

  PG_STAGE_A(0, 0, 0); PG_STAGE_B(0, 0, 0); PG_STAGE_A(0, 1, 0); PG_STAGE_B(0, 1, 0);
  VMBAR(3);

  const int NT = K >> 6;  // 32
  int t = 0;
  for (; t + 2 < NT; t += 2) { PTILE(t, 0, 1); PTILE(t + 1, 1, 0); }
  PTILE(t, 0, 1);

  PLDS_B(1, 0); PLDS_A(1, 0); PMFMA(0, 4);
  VMBAR(0);
  PLDS_B(1, 1); PLDS_A(1, 1); PMFMA(0, 4);

#undef PG_STAGE_A
#undef PG_STAGE_B
#undef PLDS_A
#undef PLDS_B
#undef PMFMA
#undef PTILE
#undef VMBAR
#undef SCHED0

#pragma unroll
  for (int mt = 0; mt < 4; ++mt)
#pragma unroll
    for (int nt = 0; nt < 4; ++nt) {
      const int col = n0 + wn * 64 + nt * 16 + r16;
      const int rowbase = m0 + wm * 64 + mt * 16 + quad * 4;
#pragma unroll
      for (int r = 0; r < 4; ++r)
        C[(long)(rowbase + r) * N + col] = acc[mt][nt][r];
    }
}

// ---------------------------------------------------------------------------
// Flash attention v6 (round-14, verified): block = (b, h, 128 q) = 8 waves x
// 16 q each, 512 thr.  Dual-buffered 32-key K/V tiles, cross-barrier glds
// prefetch.  LDS 43008 B -> 2 blocks/CU = 16 waves/CU.  Conflict-free P
// layout: P[row][col] at row*40 + (((col>>3) ^ (row>>2))<<3) + (col&7).
// Q arrives pre-scaled by scale*log2e.
// ---------------------------------------------------------------------------
__global__ __launch_bounds__(512, 4) void attn_kernel(const uint16_t* __restrict__ Q,
                                                      const uint16_t* __restrict__ K,
                                                      const uint16_t* __restrict__ Vt,
                                                      const float* __restrict__ bias,
                                                      uint16_t* __restrict__ O) {
  __shared__ __align__(16) uint16_t Ks[2][32 * 128];   // [key][chunk16 ^ (key&7)]
  __shared__ __align__(16) uint16_t Vts[2][128 * 32];  // [dim][keychunk ^ (dim&3)]
  __shared__ __align__(16) uint16_t Ps[8][16 * 40];    // per-wave P, conflict-free
  const int tid = threadIdx.x;
  const int lane = tid & 63;
  const int w = tid >> 6;                              // 8 waves
  const int r16 = lane & 15, quad = lane >> 4;
  const int h = blockIdx.y, b = blockIdx.z;
  const int qbase = blockIdx.x * 128 + w * 16;         // 16 q rows per wave

  // Q fragment: rows r16, k = c*32 + quad*8 + j
  bf16x8 qf[4];
  {
    const uint16_t* qb = Q + ((long)(b * 2048 + qbase + r16)) * 2048 + h * 128 + quad * 8;
#pragma unroll
    for (int c = 0; c < 4; ++c) qf[c] = *(const bf16x8*)(qb + c * 32);
  }
  f32x4 oacc[8] = {};
  float li[4] = {};

  uint16_t* PsW = &Ps[w][0];
  const float* brow = bias + b * 2048;

  // staging: wave w owns K chunk w (keys 4w..4w+3) and V chunk w (dims 16w..16w+15)
  const int kkey = 4 * w + quad;                        // key this lane stages
  const uint16_t* kg = K + ((long)(b * 2048 + kkey)) * 2048 + h * 128
                         + 8 * (r16 ^ (kkey & 7));
  const int vdim = 16 * w + (lane >> 2);
  const uint16_t* vg = Vt + ((long)((b * 16 + h) * 128 + vdim)) * 2048
                          + 8 * ((lane & 3) ^ ((lane >> 2) & 3));

  // prologue: stage tile 0 into buffer 0
  glds16(kg, &Ks[0][w * 512]);
  glds16(vg, &Vts[0][w * 512]);
  kg += 32 * 2048;
  vg += 32;
  float bn0 = brow[r16], bn1 = brow[16 + r16];

  auto body = [&](int k0, const uint16_t* Kc, const uint16_t* Vc,
                  uint16_t* Kn, uint16_t* Vn, bool pf) {
    __syncthreads();
    const float bc0 = bn0, bc1 = bn1;
    if (pf) {
      glds16(kg, Kn + w * 512);
      glds16(vg, Vn + w * 512);
      kg += 32 * 2048;
      vg += 32;
      bn0 = brow[k0 + 32 + r16];
      bn1 = brow[k0 + 48 + r16];
    }
    // QK^T -> exp -> P-store (conflict-free windows)
#pragma unroll
    for (int ct = 0; ct < 2; ++ct) {
      const int key = ct * 16 + r16;
      const int kb = key & 7;
      bf16x8 kf[4];
#pragma unroll
      for (int c = 0; c < 4; ++c)
        kf[c] = *(const bf16x8*)(Kc + key * 128 + ((4 * c + quad) ^ kb) * 8);
      const float bv = ct ? bc1 : bc0;
      const int pc = ct * 2 + (r16 >> 3);              // col>>3
      f32x4 s = {};
#pragma unroll
      for (int c = 0; c < 4; ++c)
        s = __builtin_amdgcn_mfma_f32_16x16x32_bf16(qf[c], kf[c], s, 0, 0, 0);
#pragma unroll
      for (int r = 0; r < 4; ++r) {
        const float p = __builtin_amdgcn_exp2f(s[r] + bv);
        const uint32_t pb = f_as_u(p) + 0x8000u;       // round-half-up to bf16
        const int row = quad * 4 + r;                  // q row (row>>2 == quad)
        PsW[row * 40 + ((pc ^ quad) << 3) + (r16 & 7)] = (uint16_t)(pb >> 16);
        li[r] += u_as_f(pb & 0xffff0000u);
      }
    }
    // PV: pa row = r16, logical col window = quad -> phys window quad^(r16>>2)
    bf16x8 pa = *(const bf16x8*)(PsW + r16 * 40 + ((quad ^ (r16 >> 2)) << 3));
#pragma unroll
    for (int nt = 0; nt < 8; ++nt) {
      const int dim = nt * 16 + r16;
      bf16x8 vf = *(const bf16x8*)(Vc + dim * 32 + ((quad ^ (dim & 3)) << 3));
      oacc[nt] = __builtin_amdgcn_mfma_f32_16x16x32_bf16(pa, vf, oacc[nt], 0, 0, 0);
    }
  };

  for (int kt2 = 0; kt2 < 32; ++kt2) {
    body(64 * kt2,      &Ks[0][0], &Vts[0][0], &Ks[1][0], &Vts[1][0], true);
    body(64 * kt2 + 32, &Ks[1][0], &Vts[1][0], &Ks[0][0], &Vts[0][0], kt2 < 31);
  }

  // li[r] partial over keys == r16 (mod 16); reduce across r16 only (off<16)
#pragma unroll
  for (int off = 1; off < 16; off <<= 1)
#pragma unroll
    for (int r = 0; r < 4; ++r) li[r] += __shfl_xor(li[r], off);

  uint16_t* ob = O + ((long)(b * 2048 + qbase)) * 2048 + h * 128;
  float inv_l[4];
#pragma unroll
  for (int r = 0; r < 4; ++r) inv_l[r] = 1.0f / li[r];
#pragma unroll
  for (int nt = 0; nt < 8; ++nt)
#pragma unroll
    for (int r = 0; r < 4; ++r)
      ob[(long)(quad * 4 + r) * 2048 + nt * 16 + r16] = f2bf(oacc[nt][r] * inv_l[r]);
}

extern "C" void kernel_launch(void* const* d_in, const int* in_sizes, int n_in,
                              void* d_out, int out_size, void* d_ws, size_t ws_size,
                              hipStream_t stream) {
  const float* x   = (const float*)d_in[0];
  const float* enc = (const float*)d_in[1];
  const int*   msk = (const int*)d_in[2];
  const float* Wq  = (const float*)d_in[3];
  const float* Wk  = (const float*)d_in[4];
  const float* Wv  = (const float*)d_in[5];
  const float* Wo  = (const float*)d_in[6];
  float* out = (float*)d_out;

  const long NELT = 8L * 1024 * 1024;  // 4096 x 2048 elems
  const long WELT = 4L * 1024 * 1024;  // 2048 x 2048 elems
  // d_ws (80 MiB + 16 KiB used): Qb[8M] Kb[8M] Vtb[8M] W4[16M] | bias
  uint16_t* Qb  = (uint16_t*)d_ws;
  uint16_t* Kb  = Qb + NELT;
  uint16_t* Vtb = Kb + NELT;
  uint16_t* W4  = Vtb + NELT;
  float* biasb  = (float*)(W4 + 4 * WELT);
  // d_out doubles as scratch for bf16 activations until the final GEMM overwrites it.
  uint16_t* xb   = (uint16_t*)d_out;        // 8M elems = 16 MB
  uint16_t* encb = xb + NELT;               // 8M elems = 16 MB (total 32 MB = out size)
  uint16_t* Ob   = W4;                      // Wq/Wk region dead after QKV GEMM

  const float cs_exp = 0.088388347648318447f * LOG2E;  // folded into Q

  convert_f32_bf16<<<(int)(NELT / 2048), 256, 0, stream>>>(x, xb);
  convert_f32_bf16<<<(int)(NELT / 2048), 256, 0, stream>>>(enc, encb);
  convert_w4<<<8192, 256, 0, stream>>>(Wq, Wk, Wv, Wo, W4);
  mask_bias<<<16, 256, 0, stream>>>(msk, biasb);

  // QKV mega-GEMM: 256^2 tiles, grid 16x24 = 384 blocks, 2 blocks/CU
  gemm256<<<384, 512, 0, stream>>>(xb, encb, W4, Qb, Kb, Vtb,
                                   4096, 6144, 2048, cs_exp);

  attn_kernel<<<dim3(16, 16, 2), 512, 0, stream>>>(Qb, Kb, Vtb, biasb, Ob);

  // Final projection: 128x256 tiles, grid 32x8 = 256 blocks = one full round.
  gemm_proj<<<256, 512, 0, stream>>>(Ob, W4 + 3 * WELT, out, 4096, 2048, 2048);
}

// Round 8
// 447.669 us; speedup vs baseline: 2.9455x; 2.9455x over previous
//
#include <hip/hip_runtime.h>
#include <stdint.h>

// B=2, SQ=SK=2048, HIDDEN=2048, HEADS=16, HEAD_DIM=128.
// DTYPE MODEL (verified): inputs fp32, mask int32, OUTPUT fp32. Internal bf16 MFMA.
// Round 16: REVERT to round-14 state (best measured: 445 us; QKV 145 us x2
// containers). Round-15 lesson: launch_bounds(512,4) on the 8-wave 256^2 tile
// forces VGPR<=128 < acc(128)+misc(40) -> accumulator spills to scratch
// (WRITE_SIZE 50MB -> 2.8GB, MfmaUtil 4%). The 128x64 wave tile structurally
// caps at 2 waves/SIMD; never request more.  Only additive change this round:
// fuse the two x/enc bf16 converts into one launch (convert_xe).

#define LOG2E 1.44269504088896340736f
#define INV2PI 0.15915494309189535f

typedef __attribute__((ext_vector_type(8))) short bf16x8;
typedef __attribute__((ext_vector_type(8))) uint16_t u16x8;
typedef __attribute__((ext_vector_type(4))) uint16_t u16x4;
typedef __attribute__((ext_vector_type(4))) float f32x4;

__device__ __forceinline__ uint16_t f2bf(float f) {
  union { float f; uint32_t i; } v; v.f = f;
  uint32_t x = v.i;
  return (uint16_t)((x + 0x7fffu + ((x >> 16) & 1u)) >> 16);  // RTN-even
}
__device__ __forceinline__ uint32_t f_as_u(float f) { union { float f; uint32_t u; } v; v.f = f; return v.u; }
__device__ __forceinline__ float u_as_f(uint32_t u) { union { uint32_t u; float f; } v; v.u = u; return v.f; }
__device__ __forceinline__ void glds16(const void* g, void* l) {
  __builtin_amdgcn_global_load_lds((const __attribute__((address_space(1))) void*)g,
                                   (__attribute__((address_space(3))) void*)l, 16, 0, 0);
}

// x and enc -> bf16 in one launch. 8192 blocks: 4096 per tensor.
__global__ __launch_bounds__(256) void convert_xe(const float* __restrict__ x,
                                                  const float* __restrict__ enc,
                                                  uint16_t* __restrict__ xb,
                                                  uint16_t* __restrict__ encb) {
  const int blk = blockIdx.x;
  const float* src = (blk < 4096) ? x : enc;
  uint16_t* dst = (blk < 4096) ? xb : encb;
  const long off = ((long)(blk & 4095) * 256 + threadIdx.x) * 8;
  const f32x4 a = *(const f32x4*)(src + off);
  const f32x4 b = *(const f32x4*)(src + off + 4);
  u16x8 o;
#pragma unroll
  for (int j = 0; j < 4; ++j) { o[j] = f2bf(a[j]); o[4 + j] = f2bf(b[j]); }
  *(u16x8*)(dst + off) = o;
}

// All four weights -> one contiguous bf16 buffer W4 = [Wq|Wk|Wv|Wo], 4M elems each.
__global__ __launch_bounds__(256) void convert_w4(const float* __restrict__ Wq,
                                                  const float* __restrict__ Wk,
                                                  const float* __restrict__ Wv,
                                                  const float* __restrict__ Wo,
                                                  uint16_t* __restrict__ W4) {
  const int blk = blockIdx.x;        // 8192 blocks, 2048 per section
  const int sec = blk >> 11;
  const long off = ((long)(blk & 2047) * 256 + threadIdx.x) * 8;
  const float* src = (sec == 0) ? Wq : (sec == 1) ? Wk : (sec == 2) ? Wv : Wo;
  const f32x4 a = *(const f32x4*)(src + off);
  const f32x4 b = *(const f32x4*)(src + off + 4);
  u16x8 o;
#pragma unroll
  for (int j = 0; j < 4; ++j) { o[j] = f2bf(a[j]); o[4 + j] = f2bf(b[j]); }
  *(u16x8*)(W4 + (long)sec * 4194304 + off) = o;
}

// mask int -> additive softmax bias float (0 or -inf). 4096 elems.
__global__ __launch_bounds__(256) void mask_bias(const int* __restrict__ m,
                                                 float* __restrict__ bias) {
  const int i = blockIdx.x * 256 + threadIdx.x;
  bias[i] = m[i] ? 0.0f : -__builtin_inff();
}

// c is the section-local column; C has row stride 2048.
__device__ __forceinline__ void epi_rope_store(uint16_t* C, const f32x4& a, int rowbase,
                                               int c, float oscale) {
  const int f = (c >> 1) & 63;
  const float inv = __builtin_amdgcn_exp2f((float)f * (-13.287712379549449f / 64.0f));
  const float sgn = (c & 1) ? 1.0f : -1.0f;
#pragma unroll
  for (int r = 0; r < 4; ++r) {
    const float val = a[r];
    const float partner = __shfl_xor(val, 1);
    const int s = (rowbase + r) & 2047;
    const float rev = __builtin_amdgcn_fractf((float)s * inv * INV2PI);
    const float sn = __builtin_amdgcn_sinf(rev);
    const float cs = __builtin_amdgcn_cosf(rev);
    C[(long)(rowbase + r) * 2048 + c] = f2bf((val * cs + sgn * partner * sn) * oscale);
  }
}

// ---------------------------------------------------------------------------
// QKV mega-GEMM: 256x256 tile, BK=64, 512 threads = 8 waves (2M x 4N).
// Round-10/12/14 verified structure (145-146 us on two containers):
// 2 counted-vmcnt syncs per K-tile, 4 glds in flight across each barrier.
// LDS map: [256 rows][4 slots of 8]; phys slot p at row r holds logical
// k-slot p ^ ((r>>1)&3); staged via pre-swizzled global source (rule 21).
// NOTE: 128x64 wave tile => acc 128 regs + ~40 misc => 2 waves/SIMD cap;
// do NOT raise the launch_bounds min-waves (r15: forces scratch spill).
// ---------------------------------------------------------------------------
__global__ __launch_bounds__(512, 2) void gemm256(const uint16_t* __restrict__ A0,
                                                  const uint16_t* __restrict__ A1,
                                                  const uint16_t* __restrict__ W,
                                                  uint16_t* __restrict__ Qb,
                                                  uint16_t* __restrict__ Kb,
                                                  uint16_t* __restrict__ Vtb,
                                                  int M, int N, int K, float oscale) {
  __shared__ __align__(16) uint16_t As[2][2][8192];  // [buf][kk][256*32] = 64 KiB
  __shared__ __align__(16) uint16_t Bs[2][2][8192];  // 64 KiB
  const int tid = threadIdx.x;
  const int lane = tid & 63;
  const int w = tid >> 6;
  const int r16 = lane & 15, quad = lane >> 4;
  const int wm = w >> 2, wn = w & 3;

  // bijective XCD swizzle (nwg % 8 == 0), column-chunked.
  const int nby = M >> 8;
  const int nwg = gridDim.x;
  const int wg = ((int)blockIdx.x & 7) * (nwg >> 3) + ((int)blockIdx.x >> 3);
  const int by = wg % nby, bx = wg / nby;
  const int m0 = by << 8, n0 = bx << 8;

  const uint16_t* A = (n0 >= 2048) ? A1 : A0;

  // staging: wave w owns chunks 2w, 2w+1 (16 rows each) of every half-tile
  const int srow = 2 * w * 16 + (lane >> 2);           // rows srow, srow+16
  const int ssl = (lane & 3) ^ ((srow >> 1) & 3);      // same for srow+16
  const uint16_t* Ag0 = A + (long)(m0 + srow) * K + ssl * 8;
  const uint16_t* Ag1 = Ag0 + (long)16 * K;
  const uint16_t* Bg0 = W + (long)(n0 + srow) * K + ssl * 8;
  const uint16_t* Bg1 = Bg0 + (long)16 * K;
  const int ldso = w << 10;  // element offset of this wave's first 1 KiB chunk

  // fragment read offsets (elements within one [buf][kk] plane)
  const int sw = (r16 >> 1) & 3;
  const int aoff = (wm * 128 + r16) * 32 + ((quad ^ sw) << 3);
  const int boff = (wn * 64 + r16) * 32 + ((quad ^ sw) << 3);

  f32x4 acc[8][4] = {};
  bf16x8 af[4], bfr[4];

#define SCHED0() __builtin_amdgcn_sched_barrier(0)
#define G_STAGE_A(BUF, KK, T) do { \
    glds16(Ag0 + (long)(T) * 64 + (KK) * 32, &As[BUF][KK][ldso]); \
    glds16(Ag1 + (long)(T) * 64 + (KK) * 32, &As[BUF][KK][ldso + 512]); } while (0)
#define G_STAGE_B(BUF, KK, T) do { \
    glds16(Bg0 + (long)(T) * 64 + (KK) * 32, &Bs[BUF][KK][ldso]); \
    glds16(Bg1 + (long)(T) * 64 + (KK) * 32, &Bs[BUF][KK][ldso + 512]); } while (0)
#define LDS_B(BUF, KK) do { _Pragma("unroll") \
    for (int i = 0; i < 4; ++i) bfr[i] = *(const bf16x8*)&Bs[BUF][KK][boff + i * 512]; } while (0)
#define LDS_A(BUF, KK, MH) do { _Pragma("unroll") \
    for (int i = 0; i < 4; ++i) af[i] = *(const bf16x8*)&As[BUF][KK][aoff + ((MH) * 4 + i) * 512]; } while (0)
#define MFMA16(MH) do { __builtin_amdgcn_s_setprio(1); _Pragma("unroll") \
    for (int mi = 0; mi < 4; ++mi) { _Pragma("unroll") \
      for (int nt = 0; nt < 4; ++nt) \
        acc[(MH) * 4 + mi][nt] = __builtin_amdgcn_mfma_f32_16x16x32_bf16(af[mi], bfr[nt], acc[(MH) * 4 + mi][nt], 0, 0, 0); } \
    __builtin_amdgcn_s_setprio(0); } while (0)
#define VMBAR(NN) do { SCHED0(); \
    asm volatile("s_waitcnt vmcnt(" #NN ")" ::: "memory"); \
    __builtin_amdgcn_s_barrier(); \
    SCHED0(); } while (0)
#define TILE_ITER(T, BC, BN) do { \
    G_STAGE_A(BN, 0, (T) + 1); LDS_B(BC, 0); LDS_A(BC, 0, 0); MFMA16(0); \
    G_STAGE_B(BN, 0, (T) + 1); LDS_A(BC, 0, 1); MFMA16(1); \
    VMBAR(4); \
    G_STAGE_A(BN, 1, (T) + 1); LDS_B(BC, 1); LDS_A(BC, 1, 0); MFMA16(0); \
    G_STAGE_B(BN, 1, (T) + 1); LDS_A(BC, 1, 1); MFMA16(1); \
    VMBAR(4); } while (0)

  // prologue: stage tile 0 fully; land k0 halves, keep k1 halves in flight
  G_STAGE_A(0, 0, 0); G_STAGE_B(0, 0, 0); G_STAGE_A(0, 1, 0); G_STAGE_B(0, 1, 0);
  VMBAR(4);

  const int NT = K >> 6;  // 32 (even); tiles 0..NT-1
  int t = 0;
  for (; t + 2 < NT; t += 2) { TILE_ITER(t, 0, 1); TILE_ITER(t + 1, 1, 0); }
  TILE_ITER(t, 0, 1);  // t == NT-2 (even): stages tile NT-1 into buf 1

  // peeled tail tile NT-1 (buf 1): no staging; drain its k1 at mid-tile
  LDS_B(1, 0); LDS_A(1, 0, 0); MFMA16(0);
  LDS_A(1, 0, 1); MFMA16(1);
  VMBAR(0);
  LDS_B(1, 1); LDS_A(1, 1, 0); MFMA16(0);
  LDS_A(1, 1, 1); MFMA16(1);

#undef G_STAGE_A
#undef G_STAGE_B
#undef LDS_A
#undef LDS_B
#undef TILE_ITER

#pragma unroll
  for (int mt = 0; mt < 8; ++mt)
#pragma unroll
    for (int nt = 0; nt < 4; ++nt) {
      const int col = n0 + wn * 64 + nt * 16 + r16;
      const int rowbase = m0 + wm * 128 + mt * 16 + quad * 4;
      if (n0 < 2048) {
        epi_rope_store(Qb, acc[mt][nt], rowbase, col, oscale);       // Q
      } else if (n0 < 4096) {
        epi_rope_store(Kb, acc[mt][nt], rowbase, col - 2048, 1.0f);  // K
      } else {
        const int c = col - 4096;
        const int h = c >> 7, d = c & 127;
        const int b = rowbase >> 11, s = rowbase & 2047;
        u16x4 pk;
#pragma unroll
        for (int r = 0; r < 4; ++r) pk[r] = f2bf(acc[mt][nt][r]);
        *(u16x4*)(Vtb + (long)((b * 16 + h) * 128 + d) * 2048 + s) = pk;
      }
    }
}

// ---------------------------------------------------------------------------
// Final projection: BM=128, BN=256, BK=64, 8 waves (2M x 4N) -> wave 64x64.
// Grid 32x8 = 256 blocks = one full round on 256 CUs.  vmcnt(3) ledger.
// LDS: As 2x2x[128x32]=32K + Bs 2x2x[256x32]=64K = 96 KiB.
// ---------------------------------------------------------------------------
__global__ __launch_bounds__(512, 2) void gemm_proj(const uint16_t* __restrict__ A0,
                                                    const uint16_t* __restrict__ W,
                                                    float* __restrict__ C,
                                                    int M, int N, int K) {
  __shared__ __align__(16) uint16_t As[2][2][4096];  // [buf][kk][128*32] = 32 KiB
  __shared__ __align__(16) uint16_t Bs[2][2][8192];  // [buf][kk][256*32] = 64 KiB
  const int tid = threadIdx.x;
  const int lane = tid & 63;
  const int w = tid >> 6;
  const int r16 = lane & 15, quad = lane >> 4;
  const int wm = w >> 2, wn = w & 3;

  const int nby = M >> 7;  // BM=128
  const int nwg = gridDim.x;
  const int wg = ((int)blockIdx.x & 7) * (nwg >> 3) + ((int)blockIdx.x >> 3);
  const int by = wg % nby, bx = wg / nby;
  const int m0 = by << 7, n0 = bx << 8;

  // staging: wave w owns A chunk w (16 rows) and B chunks 2w, 2w+1
  const int sa_row = 16 * w + (lane >> 2);
  const int sb_row = 32 * w + (lane >> 2);
  const int ssl = (lane & 3) ^ (((lane >> 2) >> 1) & 3);
  const uint16_t* Ag = A0 + (long)(m0 + sa_row) * K + ssl * 8;
  const uint16_t* Bg0 = W + (long)(n0 + sb_row) * K + ssl * 8;
  const uint16_t* Bg1 = Bg0 + (long)16 * K;

  const int sw = (r16 >> 1) & 3;
  const int aoff = (wm * 64 + r16) * 32 + ((quad ^ sw) << 3);
  const int boff = (wn * 64 + r16) * 32 + ((quad ^ sw) << 3);

  f32x4 acc[4][4] = {};
  bf16x8 af[4], bfr[4];

#define SCHED0() __builtin_amdgcn_sched_barrier(0)
#define VMBAR(NN) do { SCHED0(); \
    asm volatile("s_waitcnt vmcnt(" #NN ")" ::: "memory"); \
    __builtin_amdgcn_s_barrier(); \
    SCHED0(); } while (0)
#define PG_STAGE_A(BUF, KK, T) \
    glds16(Ag + (long)(T) * 64 + (KK) * 32, &As[BUF][KK][w * 512])
#define PG_STAGE_B(BUF, KK, T) do { \
    glds16(Bg0 + (long)(T) * 64 + (KK) * 32, &Bs[BUF][KK][2 * w * 512]); \
    glds16(Bg1 + (long)(T) * 64 + (KK) * 32, &Bs[BUF][KK][2 * w * 512 + 512]); } while (0)
#define PLDS_B(BUF, KK) do { _Pragma("unroll") \
    for (int i = 0; i < 4; ++i) bfr[i] = *(const bf16x8*)&Bs[BUF][KK][boff + i * 512]; } while (0)
#define PLDS_A(BUF, KK) do { _Pragma("unroll") \
    for (int i = 0; i < 4; ++i) af[i] = *(const bf16x8*)&As[BUF][KK][aoff + i * 512]; } while (0)
#define PMFMA(MT0, MT1) do { __builtin_amdgcn_s_setprio(1); _Pragma("unroll") \
    for (int mi = (MT0); mi < (MT1); ++mi) { _Pragma("unroll") \
      for (int nt = 0; nt < 4; ++nt) \
        acc[mi][nt] = __builtin_amdgcn_mfma_f32_16x16x32_bf16(af[mi], bfr[nt], acc[mi][nt], 0, 0, 0); } \
    __builtin_amdgcn_s_setprio(0); } while (0)
#define PTILE(T, BC, BN) do { \
    PG_STAGE_A(BN, 0, (T) + 1); PLDS_B(BC, 0); PLDS_A(BC, 0); PMFMA(0, 2); \
    PG_STAGE_B(BN, 0, (T) + 1); PMFMA(2, 4); \
    VMBAR(3); \
    PG_STAGE_A(BN, 1, (T) + 1); PLDS_B(BC, 1); PLDS_A(BC, 1); PMFMA(0, 2); \
    PG_STAGE_B(BN, 1, (T) + 1); PMFMA(2, 4); \
    VMBAR(3); } while (0)

  PG_STAGE_A(0, 0, 0); PG_STAGE_B(0, 0, 0); PG_STAGE_A(0, 1, 0); PG_STAGE_B(0, 1, 0);
  VMBAR(3);

  const int NT = K >> 6;  // 32
  int t = 0;
  for (; t + 2 < NT; t += 2) { PTILE(t, 0, 1); PTILE(t + 1, 1, 0); }
  PTILE(t, 0, 1);

  PLDS_B(1, 0); PLDS_A(1, 0); PMFMA(0, 4);
  VMBAR(0);
  PLDS_B(1, 1); PLDS_A(1, 1); PMFMA(0, 4);

#undef PG_STAGE_A
#undef PG_STAGE_B
#undef PLDS_A
#undef PLDS_B
#undef PMFMA
#undef PTILE
#undef VMBAR
#undef SCHED0

#pragma unroll
  for (int mt = 0; mt < 4; ++mt)
#pragma unroll
    for (int nt = 0; nt < 4; ++nt) {
      const int col = n0 + wn * 64 + nt * 16 + r16;
      const int rowbase = m0 + wm * 64 + mt * 16 + quad * 4;
#pragma unroll
      for (int r = 0; r < 4; ++r)
        C[(long)(rowbase + r) * N + col] = acc[mt][nt][r];
    }
}

// ---------------------------------------------------------------------------
// Flash attention v6 (round-14, verified): block = (b, h, 128 q) = 8 waves x
// 16 q each, 512 thr.  Dual-buffered 32-key K/V tiles, cross-barrier glds
// prefetch.  LDS 43008 B -> 2 blocks/CU = 16 waves/CU.  Conflict-free P
// layout: P[row][col] at row*40 + (((col>>3) ^ (row>>2))<<3) + (col&7).
// Q arrives pre-scaled by scale*log2e.
// ---------------------------------------------------------------------------
__global__ __launch_bounds__(512, 4) void attn_kernel(const uint16_t* __restrict__ Q,
                                                      const uint16_t* __restrict__ K,
                                                      const uint16_t* __restrict__ Vt,
                                                      const float* __restrict__ bias,
                                                      uint16_t* __restrict__ O) {
  __shared__ __align__(16) uint16_t Ks[2][32 * 128];   // [key][chunk16 ^ (key&7)]
  __shared__ __align__(16) uint16_t Vts[2][128 * 32];  // [dim][keychunk ^ (dim&3)]
  __shared__ __align__(16) uint16_t Ps[8][16 * 40];    // per-wave P, conflict-free
  const int tid = threadIdx.x;
  const int lane = tid & 63;
  const int w = tid >> 6;                              // 8 waves
  const int r16 = lane & 15, quad = lane >> 4;
  const int h = blockIdx.y, b = blockIdx.z;
  const int qbase = blockIdx.x * 128 + w * 16;         // 16 q rows per wave

  // Q fragment: rows r16, k = c*32 + quad*8 + j
  bf16x8 qf[4];
  {
    const uint16_t* qb = Q + ((long)(b * 2048 + qbase + r16)) * 2048 + h * 128 + quad * 8;
#pragma unroll
    for (int c = 0; c < 4; ++c) qf[c] = *(const bf16x8*)(qb + c * 32);
  }
  f32x4 oacc[8] = {};
  float li[4] = {};

  uint16_t* PsW = &Ps[w][0];
  const float* brow = bias + b * 2048;

  // staging: wave w owns K chunk w (keys 4w..4w+3) and V chunk w (dims 16w..16w+15)
  const int kkey = 4 * w + quad;                        // key this lane stages
  const uint16_t* kg = K + ((long)(b * 2048 + kkey)) * 2048 + h * 128
                         + 8 * (r16 ^ (kkey & 7));
  const int vdim = 16 * w + (lane >> 2);
  const uint16_t* vg = Vt + ((long)((b * 16 + h) * 128 + vdim)) * 2048
                          + 8 * ((lane & 3) ^ ((lane >> 2) & 3));

  // prologue: stage tile 0 into buffer 0
  glds16(kg, &Ks[0][w * 512]);
  glds16(vg, &Vts[0][w * 512]);
  kg += 32 * 2048;
  vg += 32;
  float bn0 = brow[r16], bn1 = brow[16 + r16];

  auto body = [&](int k0, const uint16_t* Kc, const uint16_t* Vc,
                  uint16_t* Kn, uint16_t* Vn, bool pf) {
    __syncthreads();
    const float bc0 = bn0, bc1 = bn1;
    if (pf) {
      glds16(kg, Kn + w * 512);
      glds16(vg, Vn + w * 512);
      kg += 32 * 2048;
      vg += 32;
      bn0 = brow[k0 + 32 + r16];
      bn1 = brow[k0 + 48 + r16];
    }
    // QK^T -> exp -> P-store (conflict-free windows)
#pragma unroll
    for (int ct = 0; ct < 2; ++ct) {
      const int key = ct * 16 + r16;
      const int kb = key & 7;
      bf16x8 kf[4];
#pragma unroll
      for (int c = 0; c < 4; ++c)
        kf[c] = *(const bf16x8*)(Kc + key * 128 + ((4 * c + quad) ^ kb) * 8);
      const float bv = ct ? bc1 : bc0;
      const int pc = ct * 2 + (r16 >> 3);              // col>>3
      f32x4 s = {};
#pragma unroll
      for (int c = 0; c < 4; ++c)
        s = __builtin_amdgcn_mfma_f32_16x16x32_bf16(qf[c], kf[c], s, 0, 0, 0);
#pragma unroll
      for (int r = 0; r < 4; ++r) {
        const float p = __builtin_amdgcn_exp2f(s[r] + bv);
        const uint32_t pb = f_as_u(p) + 0x8000u;       // round-half-up to bf16
        const int row = quad * 4 + r;                  // q row (row>>2 == quad)
        PsW[row * 40 + ((pc ^ quad) << 3) + (r16 & 7)] = (uint16_t)(pb >> 16);
        li[r] += u_as_f(pb & 0xffff0000u);
      }
    }
    // PV: pa row = r16, logical col window = quad -> phys window quad^(r16>>2)
    bf16x8 pa = *(const bf16x8*)(PsW + r16 * 40 + ((quad ^ (r16 >> 2)) << 3));
#pragma unroll
    for (int nt = 0; nt < 8; ++nt) {
      const int dim = nt * 16 + r16;
      bf16x8 vf = *(const bf16x8*)(Vc + dim * 32 + ((quad ^ (dim & 3)) << 3));
      oacc[nt] = __builtin_amdgcn_mfma_f32_16x16x32_bf16(pa, vf, oacc[nt], 0, 0, 0);
    }
  };

  for (int kt2 = 0; kt2 < 32; ++kt2) {
    body(64 * kt2,      &Ks[0][0], &Vts[0][0], &Ks[1][0], &Vts[1][0], true);
    body(64 * kt2 + 32, &Ks[1][0], &Vts[1][0], &Ks[0][0], &Vts[0][0], kt2 < 31);
  }

  // li[r] partial over keys == r16 (mod 16); reduce across r16 only (off<16)
#pragma unroll
  for (int off = 1; off < 16; off <<= 1)
#pragma unroll
    for (int r = 0; r < 4; ++r) li[r] += __shfl_xor(li[r], off);

  uint16_t* ob = O + ((long)(b * 2048 + qbase)) * 2048 + h * 128;
  float inv_l[4];
#pragma unroll
  for (int r = 0; r < 4; ++r) inv_l[r] = 1.0f / li[r];
#pragma unroll
  for (int nt = 0; nt < 8; ++nt)
#pragma unroll
    for (int r = 0; r < 4; ++r)
      ob[(long)(quad * 4 + r) * 2048 + nt * 16 + r16] = f2bf(oacc[nt][r] * inv_l[r]);
}

extern "C" void kernel_launch(void* const* d_in, const int* in_sizes, int n_in,
                              void* d_out, int out_size, void* d_ws, size_t ws_size,
                              hipStream_t stream) {
  const float* x   = (const float*)d_in[0];
  const float* enc = (const float*)d_in[1];
  const int*   msk = (const int*)d_in[2];
  const float* Wq  = (const float*)d_in[3];
  const float* Wk  = (const float*)d_in[4];
  const float* Wv  = (const float*)d_in[5];
  const float* Wo  = (const float*)d_in[6];
  float* out = (float*)d_out;

  const long NELT = 8L * 1024 * 1024;  // 4096 x 2048 elems
  const long WELT = 4L * 1024 * 1024;  // 2048 x 2048 elems
  // d_ws (80 MiB + 16 KiB used): Qb[8M] Kb[8M] Vtb[8M] W4[16M] | bias
  uint16_t* Qb  = (uint16_t*)d_ws;
  uint16_t* Kb  = Qb + NELT;
  uint16_t* Vtb = Kb + NELT;
  uint16_t* W4  = Vtb + NELT;
  float* biasb  = (float*)(W4 + 4 * WELT);
  // d_out doubles as scratch for bf16 activations until the final GEMM overwrites it.
  uint16_t* xb   = (uint16_t*)d_out;        // 8M elems = 16 MB
  uint16_t* encb = xb + NELT;               // 8M elems = 16 MB (total 32 MB = out size)
  uint16_t* Ob   = W4;                      // Wq/Wk region dead after QKV GEMM

  const float cs_exp = 0.088388347648318447f * LOG2E;  // folded into Q

  convert_xe<<<8192, 256, 0, stream>>>(x, enc, xb, encb);
  convert_w4<<<8192, 256, 0, stream>>>(Wq, Wk, Wv, Wo, W4);
  mask_bias<<<16, 256, 0, stream>>>(msk, biasb);

  // QKV mega-GEMM: 256^2 tiles, grid 16x24 = 384 blocks (384 % 8 == 0)
  gemm256<<<384, 512, 0, stream>>>(xb, encb, W4, Qb, Kb, Vtb,
                                   4096, 6144, 2048, cs_exp);

  attn_kernel<<<dim3(16, 16, 2), 512, 0, stream>>>(Qb, Kb, Vtb, biasb, Ob);

  // Final projection: 128x256 tiles, grid 32x8 = 256 blocks = one full round.
  gemm_proj<<<256, 512, 0, stream>>>(Ob, W4 + 3 * WELT, out, 4096, 2048, 2048);
}